// Round 1
// baseline (1316.742 us; speedup 1.0000x reference)
//
#include <hip/hip_runtime.h>
#include <math.h>

typedef unsigned short u16;
typedef short short8 __attribute__((ext_vector_type(8)));
typedef float f32x4 __attribute__((ext_vector_type(4)));
typedef unsigned short us4 __attribute__((ext_vector_type(4)));

#define NTOK 8192
#define NEXP 8

__device__ __forceinline__ u16 f2bf(float f) {
  union { float f; unsigned u; } v; v.f = f;
  unsigned r = v.u + 0x7FFFu + ((v.u >> 16) & 1u);
  return (u16)(r >> 16);
}

// ---------------- elementwise fp32 -> bf16 cast ----------------
__global__ void cast_kernel(const float* __restrict__ in, u16* __restrict__ out, int n4) {
  int i = blockIdx.x * blockDim.x + threadIdx.x;
  if (i < n4) {
    float4 v = ((const float4*)in)[i];
    us4 o;
    o[0] = f2bf(v.x); o[1] = f2bf(v.y); o[2] = f2bf(v.z); o[3] = f2bf(v.w);
    ((us4*)out)[i] = o;
  }
}

// ------- tiled transpose+cast: fp32 in[R][C] -> bf16 out[C][R], blockIdx.z = expert -------
__global__ void transpose_cast(const float* __restrict__ in, u16* __restrict__ out, int R, int C) {
  __shared__ float tile[32][33];
  const size_t eoff = (size_t)blockIdx.z * (size_t)R * (size_t)C;
  in += eoff; out += eoff;
  int tx = threadIdx.x & 31, ty = threadIdx.x >> 5;
  int rb = blockIdx.y * 32, cb = blockIdx.x * 32;
#pragma unroll
  for (int p = 0; p < 4; ++p)
    tile[ty + p*8][tx] = in[(size_t)(rb + ty + p*8) * C + (cb + tx)];
  __syncthreads();
#pragma unroll
  for (int p = 0; p < 4; ++p)
    out[(size_t)(cb + ty + p*8) * R + (rb + tx)] = f2bf(tile[tx][ty + p*8]);
}

// ---------------- LayerNorm1: fp32 row -> bf16 row ----------------
__global__ void ln1_kernel(const float* __restrict__ x, const float* __restrict__ w,
                           const float* __restrict__ b, u16* __restrict__ xn) {
  const int t = blockIdx.x, tid = threadIdx.x;
  __shared__ float red[8];
  float4 v = ((const float4*)(x + (size_t)t * 1024))[tid];
  float s  = v.x + v.y + v.z + v.w;
  float sq = v.x*v.x + v.y*v.y + v.z*v.z + v.w*v.w;
#pragma unroll
  for (int m = 1; m < 64; m <<= 1) { s += __shfl_xor(s, m, 64); sq += __shfl_xor(sq, m, 64); }
  if ((tid & 63) == 0) { red[tid >> 6] = s; red[4 + (tid >> 6)] = sq; }
  __syncthreads();
  float S = red[0] + red[1] + red[2] + red[3];
  float Q = red[4] + red[5] + red[6] + red[7];
  float mu  = S * (1.0f / 1024.0f);
  float var = Q * (1.0f / 1024.0f) - mu * mu;
  float inv = rsqrtf(var + 1e-5f);
  float4 wv = ((const float4*)w)[tid];
  float4 bv = ((const float4*)b)[tid];
  us4 o;
  o[0] = f2bf((v.x - mu) * inv * wv.x + bv.x);
  o[1] = f2bf((v.y - mu) * inv * wv.y + bv.y);
  o[2] = f2bf((v.z - mu) * inv * wv.z + bv.z);
  o[3] = f2bf((v.w - mu) * inv * wv.w + bv.w);
  ((us4*)(xn + (size_t)t * 1024))[tid] = o;
}

// -------- LayerNorm2 + gate + top-2 routing (fp32 gate for routing fidelity) --------
__global__ void ln2_gate_kernel(const float* __restrict__ x2, const float* __restrict__ w,
                                const float* __restrict__ b, const float* __restrict__ gw,
                                const float* __restrict__ gb, u16* __restrict__ xn2,
                                int* __restrict__ cnt, int* __restrict__ list_tok,
                                float* __restrict__ list_prob) {
  const int t = blockIdx.x, tid = threadIdx.x;
  __shared__ float red[8];
  __shared__ float logits[NEXP];
  __shared__ float xrow[1024];
  float4 v = ((const float4*)(x2 + (size_t)t * 1024))[tid];
  float s  = v.x + v.y + v.z + v.w;
  float sq = v.x*v.x + v.y*v.y + v.z*v.z + v.w*v.w;
#pragma unroll
  for (int m = 1; m < 64; m <<= 1) { s += __shfl_xor(s, m, 64); sq += __shfl_xor(sq, m, 64); }
  if ((tid & 63) == 0) { red[tid >> 6] = s; red[4 + (tid >> 6)] = sq; }
  __syncthreads();
  float S = red[0] + red[1] + red[2] + red[3];
  float Q = red[4] + red[5] + red[6] + red[7];
  float mu  = S * (1.0f / 1024.0f);
  float var = Q * (1.0f / 1024.0f) - mu * mu;
  float inv = rsqrtf(var + 1e-5f);
  float4 wv = ((const float4*)w)[tid];
  float4 bv = ((const float4*)b)[tid];
  float n0 = (v.x - mu) * inv * wv.x + bv.x;
  float n1 = (v.y - mu) * inv * wv.y + bv.y;
  float n2 = (v.z - mu) * inv * wv.z + bv.z;
  float n3 = (v.w - mu) * inv * wv.w + bv.w;
  xrow[tid*4+0] = n0; xrow[tid*4+1] = n1; xrow[tid*4+2] = n2; xrow[tid*4+3] = n3;
  us4 o; o[0] = f2bf(n0); o[1] = f2bf(n1); o[2] = f2bf(n2); o[3] = f2bf(n3);
  ((us4*)(xn2 + (size_t)t * 1024))[tid] = o;
  __syncthreads();
  // gate: 8 experts x 32 lanes each
  int e = tid >> 5, l32 = tid & 31;
  const float* gwe = gw + e * 1024;
  float part = 0.0f;
  for (int i = l32; i < 1024; i += 32) part += xrow[i] * gwe[i];
#pragma unroll
  for (int m = 1; m < 32; m <<= 1) part += __shfl_xor(part, m, 64);
  if (l32 == 0) logits[e] = part + gb[e];
  __syncthreads();
  if (tid == 0) {
    float v0 = -1e30f; int e0 = 0;
#pragma unroll
    for (int i = 0; i < NEXP; ++i) { float L = logits[i]; if (L > v0) { v0 = L; e0 = i; } }
    float v1 = -1e30f; int e1 = 0;
#pragma unroll
    for (int i = 0; i < NEXP; ++i) { if (i == e0) continue; float L = logits[i]; if (L > v1) { v1 = L; e1 = i; } }
    float texp = expf(v1 - v0);
    float p0 = 1.0f / (1.0f + texp);
    float p1 = texp / (1.0f + texp);
    int s0 = atomicAdd(&cnt[e0], 1);
    list_tok[e0 * NTOK + s0] = t; list_prob[e0 * NTOK + s0] = p0;
    int s1 = atomicAdd(&cnt[e1], 1);
    list_tok[e1 * NTOK + s1] = t; list_prob[e1 * NTOK + s1] = p1;
  }
}

// ---------------- flash attention: one (b,h), 64 q-rows per block ----------------
__launch_bounds__(256)
__global__ void attn_kernel(const u16* __restrict__ qkv, u16* __restrict__ ctx) {
  const int bh = blockIdx.y;          // 0..127
  const int b = bh >> 4, h = bh & 15;
  const int q0 = blockIdx.x * 64;
  const int tokBase = b * 1024;
  __shared__ __align__(16) u16 Qs[64 * 72];
  __shared__ __align__(16) u16 Ks[64 * 72];
  __shared__ __align__(16) u16 Vts[64 * 72];
  __shared__ __align__(16) u16 Ps[64 * 72];
  const int tid = threadIdx.x;
  const int wave = tid >> 6, lane = tid & 63, g = lane >> 4, lr = lane & 15;

  {
    int r = tid >> 2, d0 = (tid & 3) * 16;
    const u16* src = qkv + (size_t)(tokBase + q0 + r) * 3072 + h * 64 + d0;
    *(short8*)&Qs[r * 72 + d0]     = *(const short8*)src;
    *(short8*)&Qs[r * 72 + d0 + 8] = *(const short8*)(src + 8);
  }
  __syncthreads();
  short8 aq0 = *(const short8*)&Qs[(wave * 16 + lr) * 72 + g * 8];
  short8 aq1 = *(const short8*)&Qs[(wave * 16 + lr) * 72 + 32 + g * 8];

  const f32x4 zf = {0.f, 0.f, 0.f, 0.f};
  f32x4 Ofr[4] = {zf, zf, zf, zf};
  float m_run[4], l_run[4];
#pragma unroll
  for (int r = 0; r < 4; ++r) { m_run[r] = -1e30f; l_run[r] = 0.f; }

  for (int kt = 0; kt < 1024; kt += 64) {
    __syncthreads();  // protect LDS reuse from previous iteration's reads
    {
      int r = tid >> 2, d0 = (tid & 3) * 16;
      const u16* ksrc = qkv + (size_t)(tokBase + kt + r) * 3072 + 1024 + h * 64 + d0;
      *(short8*)&Ks[r * 72 + d0]     = *(const short8*)ksrc;
      *(short8*)&Ks[r * 72 + d0 + 8] = *(const short8*)(ksrc + 8);
      const u16* vsrc = qkv + (size_t)(tokBase + kt + r) * 3072 + 2048 + h * 64 + d0;
      short8 v0 = *(const short8*)vsrc, v1 = *(const short8*)(vsrc + 8);
#pragma unroll
      for (int j = 0; j < 8; ++j) Vts[(d0 + j) * 72 + r] = (u16)v0[j];
#pragma unroll
      for (int j = 0; j < 8; ++j) Vts[(d0 + 8 + j) * 72 + r] = (u16)v1[j];
    }
    __syncthreads();
    // S = (Q @ K^T) * 1/8
    f32x4 sf[4];
#pragma unroll
    for (int n = 0; n < 4; ++n) sf[n] = zf;
#pragma unroll
    for (int n = 0; n < 4; ++n) {
      short8 bk0 = *(const short8*)&Ks[(n * 16 + lr) * 72 + g * 8];
      short8 bk1 = *(const short8*)&Ks[(n * 16 + lr) * 72 + 32 + g * 8];
      sf[n] = __builtin_amdgcn_mfma_f32_16x16x32_bf16(aq0, bk0, sf[n], 0, 0, 0);
      sf[n] = __builtin_amdgcn_mfma_f32_16x16x32_bf16(aq1, bk1, sf[n], 0, 0, 0);
    }
#pragma unroll
    for (int n = 0; n < 4; ++n)
#pragma unroll
      for (int r = 0; r < 4; ++r) sf[n][r] *= 0.125f;
    // online softmax (rows live in the 16-lane group sharing g)
    float mnew[4], sc[4];
#pragma unroll
    for (int r = 0; r < 4; ++r) {
      float t0 = fmaxf(fmaxf(sf[0][r], sf[1][r]), fmaxf(sf[2][r], sf[3][r]));
#pragma unroll
      for (int msk = 1; msk < 16; msk <<= 1) t0 = fmaxf(t0, __shfl_xor(t0, msk, 64));
      mnew[r] = fmaxf(m_run[r], t0);
      sc[r] = __expf(m_run[r] - mnew[r]);
      m_run[r] = mnew[r];
    }
#pragma unroll
    for (int n = 0; n < 4; ++n)
#pragma unroll
      for (int r = 0; r < 4; ++r) sf[n][r] = __expf(sf[n][r] - mnew[r]);
#pragma unroll
    for (int r = 0; r < 4; ++r) {
      float s0 = sf[0][r] + sf[1][r] + sf[2][r] + sf[3][r];
#pragma unroll
      for (int msk = 1; msk < 16; msk <<= 1) s0 += __shfl_xor(s0, msk, 64);
      l_run[r] = l_run[r] * sc[r] + s0;
    }
#pragma unroll
    for (int nd = 0; nd < 4; ++nd)
#pragma unroll
      for (int r = 0; r < 4; ++r) Ofr[nd][r] *= sc[r];
    // P -> LDS (C-layout), re-read in A-fragment layout
#pragma unroll
    for (int n = 0; n < 4; ++n)
#pragma unroll
      for (int r = 0; r < 4; ++r)
        Ps[(wave * 16 + g * 4 + r) * 72 + n * 16 + lr] = f2bf(sf[n][r]);
    __syncthreads();
    short8 ap0 = *(const short8*)&Ps[(wave * 16 + lr) * 72 + g * 8];
    short8 ap1 = *(const short8*)&Ps[(wave * 16 + lr) * 72 + 32 + g * 8];
#pragma unroll
    for (int nd = 0; nd < 4; ++nd) {
      short8 bv0 = *(const short8*)&Vts[(nd * 16 + lr) * 72 + g * 8];
      short8 bv1 = *(const short8*)&Vts[(nd * 16 + lr) * 72 + 32 + g * 8];
      Ofr[nd] = __builtin_amdgcn_mfma_f32_16x16x32_bf16(ap0, bv0, Ofr[nd], 0, 0, 0);
      Ofr[nd] = __builtin_amdgcn_mfma_f32_16x16x32_bf16(ap1, bv1, Ofr[nd], 0, 0, 0);
    }
  }
#pragma unroll
  for (int nd = 0; nd < 4; ++nd)
#pragma unroll
    for (int r = 0; r < 4; ++r) {
      int tok = tokBase + q0 + wave * 16 + g * 4 + r;
      int col = h * 64 + nd * 16 + lr;
      ctx[(size_t)tok * 1024 + col] = f2bf(Ofr[nd][r] / l_run[r]);
    }
}

// ---------------- 128x128 bf16 MFMA GEMM, C = A @ B^T (+ epilogues) ----------------
// EPI 0: qkv  (bias, bf16 out, ldc)        EPI 1: outproj (bias + resid, fp32 out)
// EPI 2: moe1 (gather rows, gelu, bf16)    EPI 3: moe2 (gather, *prob, atomicAdd fp32)
template<int EPI>
__launch_bounds__(256)
__global__ void gemm128(const u16* __restrict__ Abase, const u16* __restrict__ Bbase,
                        int K, int lda, int N, int ldc,
                        const float* __restrict__ bias,
                        const float* __restrict__ resid,
                        float* __restrict__ outF,
                        u16* __restrict__ outB,
                        const int* __restrict__ cnt,
                        const int* __restrict__ list_tok,
                        const float* __restrict__ list_prob) {
  const int tid = threadIdx.x;
  const int wave = tid >> 6, lane = tid & 63, g = lane >> 4, lr = lane & 15;
  const int n0 = blockIdx.x * 128;
  const int m0 = blockIdx.y * 128;
  const int e  = blockIdx.z;

  int M = NTOK;
  int slotBase = 0;
  const u16* Bw = Bbase;
  const float* biasp = bias;
  if constexpr (EPI == 2 || EPI == 3) {
    for (int j = 0; j < e; ++j) slotBase += cnt[j];
    M = cnt[e];
    if (m0 >= M) return;
    Bw += (size_t)e * (size_t)N * (size_t)K;
    biasp = bias + (size_t)e * N;
  }

  __shared__ __align__(16) u16 As[128 * 64];
  __shared__ __align__(16) u16 Bs[128 * 64];
  char* AsB = (char*)As;
  char* BsB = (char*)Bs;

  size_t aOff[4], bOff[4];
#pragma unroll
  for (int i = 0; i < 4; ++i) {
    int grp = i * 256 + tid;
    int r = grp >> 3;
    int ce = (grp & 7) * 8;
    int arow;
    if constexpr (EPI == 2) {
      int ridx = m0 + r; if (ridx > M - 1) ridx = M - 1;
      arow = list_tok[e * NTOK + ridx];
    } else if constexpr (EPI == 3) {
      int ridx = m0 + r; if (ridx > M - 1) ridx = M - 1;
      arow = slotBase + ridx;
    } else {
      arow = m0 + r;
    }
    aOff[i] = (size_t)arow * (size_t)lda + (size_t)ce;
    bOff[i] = (size_t)(n0 + r) * (size_t)K + (size_t)ce;
  }

  const f32x4 zf = {0.f, 0.f, 0.f, 0.f};
  f32x4 acc[4][4];
#pragma unroll
  for (int m = 0; m < 4; ++m)
#pragma unroll
    for (int n = 0; n < 4; ++n) acc[m][n] = zf;

  const int wm = wave >> 1, wn = wave & 1;

  for (int kt = 0; kt < K; kt += 64) {
#pragma unroll
    for (int i = 0; i < 4; ++i)
      __builtin_amdgcn_global_load_lds(
        (const __attribute__((address_space(1))) unsigned int*)(const void*)(Abase + aOff[i] + kt),
        (__attribute__((address_space(3))) unsigned int*)(void*)(AsB + (i * 256 + wave * 64) * 16),
        16, 0, 0);
#pragma unroll
    for (int i = 0; i < 4; ++i)
      __builtin_amdgcn_global_load_lds(
        (const __attribute__((address_space(1))) unsigned int*)(const void*)(Bw + bOff[i] + kt),
        (__attribute__((address_space(3))) unsigned int*)(void*)(BsB + (i * 256 + wave * 64) * 16),
        16, 0, 0);
    __syncthreads();
    short8 af[4][2], bfr[4][2];
#pragma unroll
    for (int m = 0; m < 4; ++m)
#pragma unroll
      for (int kk = 0; kk < 2; ++kk)
        af[m][kk] = *(const short8*)&As[(wm * 64 + m * 16 + lr) * 64 + kk * 32 + g * 8];
#pragma unroll
    for (int n = 0; n < 4; ++n)
#pragma unroll
      for (int kk = 0; kk < 2; ++kk)
        bfr[n][kk] = *(const short8*)&Bs[(wn * 64 + n * 16 + lr) * 64 + kk * 32 + g * 8];
#pragma unroll
    for (int kk = 0; kk < 2; ++kk)
#pragma unroll
      for (int m = 0; m < 4; ++m)
#pragma unroll
        for (int n = 0; n < 4; ++n)
          acc[m][n] = __builtin_amdgcn_mfma_f32_16x16x32_bf16(af[m][kk], bfr[n][kk], acc[m][n], 0, 0, 0);
    __syncthreads();
  }

#pragma unroll
  for (int m = 0; m < 4; ++m) {
    int rloc = wm * 64 + m * 16 + g * 4;
#pragma unroll
    for (int n = 0; n < 4; ++n) {
      int gc = n0 + wn * 64 + n * 16 + lr;
      float bcol = biasp[gc];
#pragma unroll
      for (int r = 0; r < 4; ++r) {
        int ridx = m0 + rloc + r;
        float vv = acc[m][n][r] + bcol;
        if constexpr (EPI == 0) {
          outB[(size_t)ridx * ldc + gc] = f2bf(vv);
        } else if constexpr (EPI == 1) {
          size_t off = (size_t)ridx * ldc + gc;
          outF[off] = vv + resid[off];
        } else if constexpr (EPI == 2) {
          if (ridx < M)
            outB[(size_t)(slotBase + ridx) * ldc + gc] =
              f2bf(0.5f * vv * (1.0f + erff(vv * 0.70710678f)));
        } else {
          if (ridx < M) {
            int tok = list_tok[e * NTOK + ridx];
            float p = list_prob[e * NTOK + ridx];
            atomicAdd(&outF[(size_t)tok * ldc + gc], vv * p);
          }
        }
      }
    }
  }
}

// ---------------- host launch ----------------
extern "C" void kernel_launch(void* const* d_in, const int* in_sizes, int n_in,
                              void* d_out, int out_size, void* d_ws, size_t ws_size,
                              hipStream_t stream) {
  const float* x    = (const float*)d_in[0];
  const float* ln1w = (const float*)d_in[1];
  const float* ln1b = (const float*)d_in[2];
  const float* ln2w = (const float*)d_in[3];
  const float* ln2b = (const float*)d_in[4];
  const float* inw  = (const float*)d_in[5];
  const float* inb  = (const float*)d_in[6];
  const float* outw = (const float*)d_in[7];
  const float* outb = (const float*)d_in[8];
  const float* gw   = (const float*)d_in[9];
  const float* gb   = (const float*)d_in[10];
  const float* w1   = (const float*)d_in[11];
  const float* b1   = (const float*)d_in[12];
  const float* w2   = (const float*)d_in[13];
  const float* b2   = (const float*)d_in[14];
  float* out = (float*)d_out;
  char* ws = (char*)d_ws;

  // layout (bytes):
  u16* xn1 = (u16*)(ws + 0);              // 16 MiB
  u16* qkv = (u16*)(ws + 16777216);       // 48 MiB
  u16* ctx = (u16*)(ws + 67108864);       // 16 MiB
  u16* hid = (u16*)(ws + 0);              // 128 MiB (overlaps xn1/qkv/ctx, dead by then)
  u16* xn2 = (u16*)(ws + 134217728);      // 16 MiB
  u16* w1t = (u16*)(ws + 150994944);      // 64 MiB
  u16* winb  = (u16*)(ws + 218103808);    // 6 MiB
  u16* woutb = (u16*)(ws + 224395264);    // 2 MiB
  int*   cnt  = (int*)(ws + 226492416);
  int*   ltok = (int*)(ws + 226492672);   // 256 KiB
  float* lprb = (float*)(ws + 226754816); // 256 KiB  -> end 227,016,960
  // w2t: own region if ws allows; else overlap xn2+w1t (both dead after moe pass1)
  bool lateW2 = ws_size < 294125824ull;
  u16* w2t = lateW2 ? (u16*)(ws + 134217728) : (u16*)(ws + 227016960);

  // weight conversion
  cast_kernel<<<3072, 256, 0, stream>>>(inw, winb, 786432);
  cast_kernel<<<1024, 256, 0, stream>>>(outw, woutb, 262144);
  transpose_cast<<<dim3(128, 32, 8), 256, 0, stream>>>(w1, w1t, 1024, 4096);
  if (!lateW2) transpose_cast<<<dim3(32, 128, 8), 256, 0, stream>>>(w2, w2t, 4096, 1024);

  // attention sub-block
  ln1_kernel<<<8192, 256, 0, stream>>>(x, ln1w, ln1b, xn1);
  gemm128<0><<<dim3(24, 64, 1), 256, 0, stream>>>(xn1, winb, 1024, 1024, 3072, 3072,
                                                  inb, nullptr, nullptr, qkv, nullptr, nullptr, nullptr);
  attn_kernel<<<dim3(16, 128), 256, 0, stream>>>(qkv, ctx);
  gemm128<1><<<dim3(8, 64, 1), 256, 0, stream>>>(ctx, woutb, 1024, 1024, 1024, 1024,
                                                 outb, x, out, nullptr, nullptr, nullptr, nullptr);

  // MoE sub-block (top-2 only: 4x fewer FLOPs than reference's dense-all-experts)
  hipMemsetAsync(cnt, 0, 32, stream);
  ln2_gate_kernel<<<8192, 256, 0, stream>>>(out, ln2w, ln2b, gw, gb, xn2, cnt, ltok, lprb);
  gemm128<2><<<dim3(32, 64, 8), 256, 0, stream>>>(xn2, w1t, 1024, 1024, 4096, 4096,
                                                  b1, nullptr, nullptr, hid, cnt, ltok, lprb);
  if (lateW2) transpose_cast<<<dim3(32, 128, 8), 256, 0, stream>>>(w2, w2t, 4096, 1024);
  gemm128<3><<<dim3(8, 64, 8), 256, 0, stream>>>(hid, w2t, 4096, 4096, 1024, 1024,
                                                 b2, nullptr, out, nullptr, cnt, ltok, lprb);
}

// Round 2
// 1082.290 us; speedup vs baseline: 1.2166x; 1.2166x over previous
//
#include <hip/hip_runtime.h>
#include <math.h>

typedef unsigned short u16;
typedef short short8 __attribute__((ext_vector_type(8)));
typedef float f32x4 __attribute__((ext_vector_type(4)));
typedef unsigned short us4 __attribute__((ext_vector_type(4)));

#define NTOK 8192
#define NEXP 8

__device__ __forceinline__ u16 f2bf(float f) {
  union { float f; unsigned u; } v; v.f = f;
  unsigned r = v.u + 0x7FFFu + ((v.u >> 16) & 1u);
  return (u16)(r >> 16);
}
__device__ __forceinline__ float bf2f(u16 u) {
  union { unsigned u; float f; } v; v.u = ((unsigned)u) << 16; return v.f;
}
__device__ __forceinline__ void gload16(const u16* src, u16* ldsDst) {
  __builtin_amdgcn_global_load_lds(
    (const __attribute__((address_space(1))) unsigned int*)(const void*)src,
    (__attribute__((address_space(3))) unsigned int*)(void*)ldsDst, 16, 0, 0);
}

// ---------------- elementwise fp32 -> bf16 cast ----------------
__global__ void cast_kernel(const float* __restrict__ in, u16* __restrict__ out, int n4) {
  int i = blockIdx.x * blockDim.x + threadIdx.x;
  if (i < n4) {
    float4 v = ((const float4*)in)[i];
    us4 o;
    o[0] = f2bf(v.x); o[1] = f2bf(v.y); o[2] = f2bf(v.z); o[3] = f2bf(v.w);
    ((us4*)out)[i] = o;
  }
}

// ------- 64x64 tiled transpose+cast: fp32 in[R][C] -> bf16 out[C][R], blockIdx.z = expert -------
__global__ void transpose_cast(const float* __restrict__ in, u16* __restrict__ out, int R, int C) {
  __shared__ float tile[64][65];
  const size_t eoff = (size_t)blockIdx.z * (size_t)R * (size_t)C;
  in += eoff; out += eoff;
  const int rb = blockIdx.y * 64, cb = blockIdx.x * 64;
  const int tid = threadIdx.x;
  const int lr4 = tid >> 4;          // 0..15
  const int lc4 = (tid & 15) * 4;    // col quad
#pragma unroll
  for (int p = 0; p < 4; ++p) {
    float4 v = *(const float4*)&in[(size_t)(rb + p * 16 + lr4) * C + cb + lc4];
    tile[p * 16 + lr4][lc4 + 0] = v.x;
    tile[p * 16 + lr4][lc4 + 1] = v.y;
    tile[p * 16 + lr4][lc4 + 2] = v.z;
    tile[p * 16 + lr4][lc4 + 3] = v.w;
  }
  __syncthreads();
  const int oc = tid >> 3;           // 0..31
  const int orr = (tid & 7) * 8;     // 8 input rows
#pragma unroll
  for (int p = 0; p < 2; ++p) {
    int c = p * 32 + oc;
    short8 o;
#pragma unroll
    for (int j = 0; j < 8; ++j) o[j] = (short)f2bf(tile[orr + j][c]);
    *(short8*)&out[(size_t)(cb + c) * R + rb + orr] = o;
  }
}

// ---------------- LayerNorm1: fp32 row -> bf16 row ----------------
__global__ void ln1_kernel(const float* __restrict__ x, const float* __restrict__ w,
                           const float* __restrict__ b, u16* __restrict__ xn) {
  const int t = blockIdx.x, tid = threadIdx.x;
  __shared__ float red[8];
  float4 v = ((const float4*)(x + (size_t)t * 1024))[tid];
  float s  = v.x + v.y + v.z + v.w;
  float sq = v.x*v.x + v.y*v.y + v.z*v.z + v.w*v.w;
#pragma unroll
  for (int m = 1; m < 64; m <<= 1) { s += __shfl_xor(s, m, 64); sq += __shfl_xor(sq, m, 64); }
  if ((tid & 63) == 0) { red[tid >> 6] = s; red[4 + (tid >> 6)] = sq; }
  __syncthreads();
  float S = red[0] + red[1] + red[2] + red[3];
  float Q = red[4] + red[5] + red[6] + red[7];
  float mu  = S * (1.0f / 1024.0f);
  float var = Q * (1.0f / 1024.0f) - mu * mu;
  float inv = rsqrtf(var + 1e-5f);
  float4 wv = ((const float4*)w)[tid];
  float4 bv = ((const float4*)b)[tid];
  us4 o;
  o[0] = f2bf((v.x - mu) * inv * wv.x + bv.x);
  o[1] = f2bf((v.y - mu) * inv * wv.y + bv.y);
  o[2] = f2bf((v.z - mu) * inv * wv.z + bv.z);
  o[3] = f2bf((v.w - mu) * inv * wv.w + bv.w);
  ((us4*)(xn + (size_t)t * 1024))[tid] = o;
}

// -------- LayerNorm2 + gate + top-2 routing (fp32 gate for routing fidelity) --------
__global__ void ln2_gate_kernel(const float* __restrict__ x2, const float* __restrict__ w,
                                const float* __restrict__ b, const float* __restrict__ gw,
                                const float* __restrict__ gb, u16* __restrict__ xn2,
                                int* __restrict__ cnt, int* __restrict__ list_tok,
                                float* __restrict__ list_prob, int* __restrict__ tok2slot) {
  const int t = blockIdx.x, tid = threadIdx.x;
  __shared__ float red[8];
  __shared__ float logits[NEXP];
  __shared__ float xrow[1024];
  float4 v = ((const float4*)(x2 + (size_t)t * 1024))[tid];
  float s  = v.x + v.y + v.z + v.w;
  float sq = v.x*v.x + v.y*v.y + v.z*v.z + v.w*v.w;
#pragma unroll
  for (int m = 1; m < 64; m <<= 1) { s += __shfl_xor(s, m, 64); sq += __shfl_xor(sq, m, 64); }
  if ((tid & 63) == 0) { red[tid >> 6] = s; red[4 + (tid >> 6)] = sq; }
  __syncthreads();
  float S = red[0] + red[1] + red[2] + red[3];
  float Q = red[4] + red[5] + red[6] + red[7];
  float mu  = S * (1.0f / 1024.0f);
  float var = Q * (1.0f / 1024.0f) - mu * mu;
  float inv = rsqrtf(var + 1e-5f);
  float4 wv = ((const float4*)w)[tid];
  float4 bv = ((const float4*)b)[tid];
  float n0 = (v.x - mu) * inv * wv.x + bv.x;
  float n1 = (v.y - mu) * inv * wv.y + bv.y;
  float n2 = (v.z - mu) * inv * wv.z + bv.z;
  float n3 = (v.w - mu) * inv * wv.w + bv.w;
  xrow[tid*4+0] = n0; xrow[tid*4+1] = n1; xrow[tid*4+2] = n2; xrow[tid*4+3] = n3;
  us4 o; o[0] = f2bf(n0); o[1] = f2bf(n1); o[2] = f2bf(n2); o[3] = f2bf(n3);
  ((us4*)(xn2 + (size_t)t * 1024))[tid] = o;
  __syncthreads();
  int e = tid >> 5, l32 = tid & 31;
  const float* gwe = gw + e * 1024;
  float part = 0.0f;
  for (int i = l32; i < 1024; i += 32) part += xrow[i] * gwe[i];
#pragma unroll
  for (int m = 1; m < 32; m <<= 1) part += __shfl_xor(part, m, 64);
  if (l32 == 0) logits[e] = part + gb[e];
  __syncthreads();
  if (tid == 0) {
    float v0 = -1e30f; int e0 = 0;
#pragma unroll
    for (int i = 0; i < NEXP; ++i) { float L = logits[i]; if (L > v0) { v0 = L; e0 = i; } }
    float v1 = -1e30f; int e1 = 0;
#pragma unroll
    for (int i = 0; i < NEXP; ++i) { if (i == e0) continue; float L = logits[i]; if (L > v1) { v1 = L; e1 = i; } }
    float texp = expf(v1 - v0);
    float p0 = 1.0f / (1.0f + texp);
    float p1 = texp / (1.0f + texp);
    int s0 = atomicAdd(&cnt[e0], 1);
    list_tok[e0 * NTOK + s0] = t; list_prob[e0 * NTOK + s0] = p0;
    int s1 = atomicAdd(&cnt[e1], 1);
    list_tok[e1 * NTOK + s1] = t; list_prob[e1 * NTOK + s1] = p1;
    if (tok2slot) {
      tok2slot[2 * t]     = e0 * NTOK + s0;
      tok2slot[2 * t + 1] = e1 * NTOK + s1;
    }
  }
}

// ---------------- flash attention: one (b,h), 64 q-rows per block ----------------
__launch_bounds__(256)
__global__ void attn_kernel(const u16* __restrict__ qkv, u16* __restrict__ ctx) {
  const int bh = blockIdx.y;
  const int b = bh >> 4, h = bh & 15;
  const int q0 = blockIdx.x * 64;
  const int tokBase = b * 1024;
  __shared__ __align__(16) u16 Qs[64 * 72];
  __shared__ __align__(16) u16 Ks[64 * 72];
  __shared__ __align__(16) u16 Vts[64 * 72];
  __shared__ __align__(16) u16 Ps[64 * 72];
  const int tid = threadIdx.x;
  const int wave = tid >> 6, lane = tid & 63, g = lane >> 4, lr = lane & 15;

  {
    int r = tid >> 2, d0 = (tid & 3) * 16;
    const u16* src = qkv + (size_t)(tokBase + q0 + r) * 3072 + h * 64 + d0;
    *(short8*)&Qs[r * 72 + d0]     = *(const short8*)src;
    *(short8*)&Qs[r * 72 + d0 + 8] = *(const short8*)(src + 8);
  }
  __syncthreads();
  short8 aq0 = *(const short8*)&Qs[(wave * 16 + lr) * 72 + g * 8];
  short8 aq1 = *(const short8*)&Qs[(wave * 16 + lr) * 72 + 32 + g * 8];

  const f32x4 zf = {0.f, 0.f, 0.f, 0.f};
  f32x4 Ofr[4] = {zf, zf, zf, zf};
  float m_run[4], l_run[4];
#pragma unroll
  for (int r = 0; r < 4; ++r) { m_run[r] = -1e30f; l_run[r] = 0.f; }

  for (int kt = 0; kt < 1024; kt += 64) {
    __syncthreads();
    {
      int r = tid >> 2, d0 = (tid & 3) * 16;
      const u16* ksrc = qkv + (size_t)(tokBase + kt + r) * 3072 + 1024 + h * 64 + d0;
      *(short8*)&Ks[r * 72 + d0]     = *(const short8*)ksrc;
      *(short8*)&Ks[r * 72 + d0 + 8] = *(const short8*)(ksrc + 8);
      const u16* vsrc = qkv + (size_t)(tokBase + kt + r) * 3072 + 2048 + h * 64 + d0;
      short8 v0 = *(const short8*)vsrc, v1 = *(const short8*)(vsrc + 8);
#pragma unroll
      for (int j = 0; j < 8; ++j) Vts[(d0 + j) * 72 + r] = (u16)v0[j];
#pragma unroll
      for (int j = 0; j < 8; ++j) Vts[(d0 + 8 + j) * 72 + r] = (u16)v1[j];
    }
    __syncthreads();
    f32x4 sf[4];
#pragma unroll
    for (int n = 0; n < 4; ++n) sf[n] = zf;
#pragma unroll
    for (int n = 0; n < 4; ++n) {
      short8 bk0 = *(const short8*)&Ks[(n * 16 + lr) * 72 + g * 8];
      short8 bk1 = *(const short8*)&Ks[(n * 16 + lr) * 72 + 32 + g * 8];
      sf[n] = __builtin_amdgcn_mfma_f32_16x16x32_bf16(aq0, bk0, sf[n], 0, 0, 0);
      sf[n] = __builtin_amdgcn_mfma_f32_16x16x32_bf16(aq1, bk1, sf[n], 0, 0, 0);
    }
#pragma unroll
    for (int n = 0; n < 4; ++n)
#pragma unroll
      for (int r = 0; r < 4; ++r) sf[n][r] *= 0.125f;
    float mnew[4], sc[4];
#pragma unroll
    for (int r = 0; r < 4; ++r) {
      float t0 = fmaxf(fmaxf(sf[0][r], sf[1][r]), fmaxf(sf[2][r], sf[3][r]));
#pragma unroll
      for (int msk = 1; msk < 16; msk <<= 1) t0 = fmaxf(t0, __shfl_xor(t0, msk, 64));
      mnew[r] = fmaxf(m_run[r], t0);
      sc[r] = __expf(m_run[r] - mnew[r]);
      m_run[r] = mnew[r];
    }
#pragma unroll
    for (int n = 0; n < 4; ++n)
#pragma unroll
      for (int r = 0; r < 4; ++r) sf[n][r] = __expf(sf[n][r] - mnew[r]);
#pragma unroll
    for (int r = 0; r < 4; ++r) {
      float s0 = sf[0][r] + sf[1][r] + sf[2][r] + sf[3][r];
#pragma unroll
      for (int msk = 1; msk < 16; msk <<= 1) s0 += __shfl_xor(s0, msk, 64);
      l_run[r] = l_run[r] * sc[r] + s0;
    }
#pragma unroll
    for (int nd = 0; nd < 4; ++nd)
#pragma unroll
      for (int r = 0; r < 4; ++r) Ofr[nd][r] *= sc[r];
#pragma unroll
    for (int n = 0; n < 4; ++n)
#pragma unroll
      for (int r = 0; r < 4; ++r)
        Ps[(wave * 16 + g * 4 + r) * 72 + n * 16 + lr] = f2bf(sf[n][r]);
    __syncthreads();
    short8 ap0 = *(const short8*)&Ps[(wave * 16 + lr) * 72 + g * 8];
    short8 ap1 = *(const short8*)&Ps[(wave * 16 + lr) * 72 + 32 + g * 8];
#pragma unroll
    for (int nd = 0; nd < 4; ++nd) {
      short8 bv0 = *(const short8*)&Vts[(nd * 16 + lr) * 72 + g * 8];
      short8 bv1 = *(const short8*)&Vts[(nd * 16 + lr) * 72 + 32 + g * 8];
      Ofr[nd] = __builtin_amdgcn_mfma_f32_16x16x32_bf16(ap0, bv0, Ofr[nd], 0, 0, 0);
      Ofr[nd] = __builtin_amdgcn_mfma_f32_16x16x32_bf16(ap1, bv1, Ofr[nd], 0, 0, 0);
    }
  }
#pragma unroll
  for (int nd = 0; nd < 4; ++nd)
#pragma unroll
    for (int r = 0; r < 4; ++r) {
      int tok = tokBase + q0 + wave * 16 + g * 4 + r;
      int col = h * 64 + nd * 16 + lr;
      ctx[(size_t)tok * 1024 + col] = f2bf(Ofr[nd][r] / l_run[r]);
    }
}

// ======= 256x256xBK64 bf16 MFMA GEMM, C = A @ B^T, 8 waves (2m x 4n), dbuf + counted vmcnt =======
// EPI 0: qkv (bias, bf16 out)      EPI 1: outproj (bias+resid, fp32)
// EPI 2: moe1 (gather A, gelu)     EPI 3: moe2 -> part bf16    EPI 4: moe2 atomic fallback
template<int EPI>
__launch_bounds__(512, 2)
__global__ void gemm256(const u16* __restrict__ Abase, const u16* __restrict__ Bbase,
                        int K, int lda, int N, int ldc,
                        const float* __restrict__ bias,
                        const float* __restrict__ resid,
                        float* __restrict__ outF,
                        u16* __restrict__ outB,
                        const int* __restrict__ cnt,
                        const int* __restrict__ list_tok,
                        const float* __restrict__ list_prob) {
  // bijective XCD-aware block remap (T1)
  const int gx = gridDim.x, gy = gridDim.y;
  int nwg = gx * gy * gridDim.z;
  int orig = blockIdx.x + blockIdx.y * gx + blockIdx.z * gx * gy;
  int q8 = nwg >> 3, r8 = nwg & 7, xcd = orig & 7, lid = orig >> 3;
  int wg = (xcd < r8 ? xcd * (q8 + 1) : r8 * (q8 + 1) + (xcd - r8) * q8) + lid;
  const int bz = wg / (gx * gy); int rem = wg - bz * gx * gy;
  const int n0 = (rem % gx) * 256;
  const int m0 = (rem / gx) * 256;
  const int e  = bz;

  int M = NTOK;
  int slotBase = 0;
  const u16* Bw = Bbase;
  const float* biasp = bias;
  if constexpr (EPI >= 2) {
    for (int j = 0; j < e; ++j) slotBase += cnt[j];
    M = cnt[e];
    if (m0 >= M) return;
    Bw += (size_t)e * (size_t)N * (size_t)K;
    biasp = bias + (size_t)e * N;
  }

  __shared__ __align__(16) u16 As[2 * 16384];   // 2 x 256x64
  __shared__ __align__(16) u16 Bs[2 * 16384];   // 2 x 256x64

  const int tid = threadIdx.x;
  const int wave = tid >> 6, lane = tid & 63, g = lane >> 4, lr = lane & 15;
  const int wm = wave >> 2, wn = wave & 3;

  // staging offsets (elements). chunk-swizzle: logical chunk = c ^ (row&7)
  size_t aoff[4], boff[4];
#pragma unroll
  for (int i = 0; i < 4; ++i) {
    int ci = i * 512 + tid;
    int row = ci >> 3, c = ci & 7;
    int lc = c ^ (row & 7);
    int arow;
    if constexpr (EPI == 2) {
      int ridx = m0 + row; if (ridx > M - 1) ridx = M - 1;
      arow = list_tok[e * NTOK + ridx];
    } else if constexpr (EPI >= 3) {
      int ridx = m0 + row; if (ridx > M - 1) ridx = M - 1;
      arow = slotBase + ridx;
    } else {
      arow = m0 + row;
    }
    aoff[i] = (size_t)arow * (size_t)lda + (size_t)(lc << 3);
    boff[i] = (size_t)(n0 + row) * (size_t)K + (size_t)(lc << 3);
  }

  const int NT = K >> 6;

#define STAGE(T) do { int _t = (T); if (_t < NT) { int _b = (_t & 1) << 14; int _kt = _t << 6; \
    _Pragma("unroll") for (int i = 0; i < 4; ++i) \
      gload16(Abase + aoff[i] + _kt, &As[_b + ((i * 512 + wave * 64) << 3)]); \
    _Pragma("unroll") for (int i = 0; i < 4; ++i) \
      gload16(Bw + boff[i] + _kt, &Bs[_b + ((i * 512 + wave * 64) << 3)]); } } while (0)

  const int sw = lr & 7;
  const int abase = (wm * 128 + lr) * 64;
  const int bbase = (wn * 64 + lr) * 64;
  const int sk0 = (g ^ sw) * 8;
  const int sk1 = ((4 + g) ^ sw) * 8;

  const f32x4 zf = {0.f, 0.f, 0.f, 0.f};
  f32x4 acc[8][4];
#pragma unroll
  for (int m = 0; m < 8; ++m)
#pragma unroll
    for (int n = 0; n < 4; ++n) acc[m][n] = zf;

  STAGE(0);
  STAGE(1);

  for (int t = 0; t < NT; ++t) {
    if (t < NT - 1) { asm volatile("s_waitcnt vmcnt(8)" ::: "memory"); }
    else           { asm volatile("s_waitcnt vmcnt(0)" ::: "memory"); }
    __builtin_amdgcn_s_barrier();
    asm volatile("" ::: "memory");
    const u16* Ab = As + ((t & 1) << 14);
    const u16* Bb = Bs + ((t & 1) << 14);
    short8 bfr[2][4];
#pragma unroll
    for (int n = 0; n < 4; ++n) bfr[0][n] = *(const short8*)&Bb[bbase + n * 1024 + sk0];
#pragma unroll
    for (int n = 0; n < 4; ++n) bfr[1][n] = *(const short8*)&Bb[bbase + n * 1024 + sk1];
    short8 afr[8];
#pragma unroll
    for (int m = 0; m < 8; ++m) afr[m] = *(const short8*)&Ab[abase + m * 1024 + sk0];
    __builtin_amdgcn_s_setprio(1);
#pragma unroll
    for (int m = 0; m < 8; ++m)
#pragma unroll
      for (int n = 0; n < 4; ++n)
        acc[m][n] = __builtin_amdgcn_mfma_f32_16x16x32_bf16(afr[m], bfr[0][n], acc[m][n], 0, 0, 0);
    __builtin_amdgcn_s_setprio(0);
#pragma unroll
    for (int m = 0; m < 8; ++m) afr[m] = *(const short8*)&Ab[abase + m * 1024 + sk1];
    asm volatile("s_waitcnt lgkmcnt(0)" ::: "memory");
    __builtin_amdgcn_s_barrier();
    asm volatile("" ::: "memory");
    STAGE(t + 2);
    __builtin_amdgcn_s_setprio(1);
#pragma unroll
    for (int m = 0; m < 8; ++m)
#pragma unroll
      for (int n = 0; n < 4; ++n)
        acc[m][n] = __builtin_amdgcn_mfma_f32_16x16x32_bf16(afr[m], bfr[1][n], acc[m][n], 0, 0, 0);
    __builtin_amdgcn_s_setprio(0);
  }
#undef STAGE

  // epilogue
#pragma unroll
  for (int m = 0; m < 8; ++m) {
    int rloc = wm * 128 + m * 16 + g * 4;
#pragma unroll
    for (int n = 0; n < 4; ++n) {
      int gc = n0 + wn * 64 + n * 16 + lr;
      float bcol = biasp[gc];
#pragma unroll
      for (int r = 0; r < 4; ++r) {
        int ridx = m0 + rloc + r;
        float vv = acc[m][n][r] + bcol;
        if constexpr (EPI == 0) {
          outB[(size_t)ridx * ldc + gc] = f2bf(vv);
        } else if constexpr (EPI == 1) {
          size_t off = (size_t)ridx * ldc + gc;
          outF[off] = vv + resid[off];
        } else if constexpr (EPI == 2) {
          if (ridx < M)
            outB[(size_t)(slotBase + ridx) * ldc + gc] =
              f2bf(0.5f * vv * (1.0f + erff(vv * 0.70710678f)));
        } else if constexpr (EPI == 3) {
          if (ridx < M)
            outB[(size_t)(slotBase + ridx) * ldc + gc] = f2bf(vv);
        } else {
          if (ridx < M) {
            int tok = list_tok[e * NTOK + ridx];
            float p = list_prob[e * NTOK + ridx];
            atomicAdd(&outF[(size_t)tok * ldc + gc], vv * p);
          }
        }
      }
    }
  }
}

// ---------------- combine: out[t] += p0*part[g0] + p1*part[g1] ----------------
__global__ void combine_kernel(const u16* __restrict__ part, const int* __restrict__ cnt,
                               const int* __restrict__ tok2slot, const float* __restrict__ lprb,
                               float* __restrict__ out) {
  const int t = blockIdx.x, tid = threadIdx.x;
  __shared__ int base[NEXP];
  if (tid == 0) {
    int b = 0;
#pragma unroll
    for (int j = 0; j < NEXP; ++j) { base[j] = b; b += cnt[j]; }
  }
  __syncthreads();
  int c0 = tok2slot[2 * t], c1 = tok2slot[2 * t + 1];
  float p0 = lprb[c0], p1 = lprb[c1];
  int g0 = base[c0 >> 13] + (c0 & 8191);
  int g1 = base[c1 >> 13] + (c1 & 8191);
  us4 a = ((const us4*)(part + (size_t)g0 * 1024))[tid];
  us4 b = ((const us4*)(part + (size_t)g1 * 1024))[tid];
  float4 o = ((const float4*)(out + (size_t)t * 1024))[tid];
  o.x += p0 * bf2f(a[0]) + p1 * bf2f(b[0]);
  o.y += p0 * bf2f(a[1]) + p1 * bf2f(b[1]);
  o.z += p0 * bf2f(a[2]) + p1 * bf2f(b[2]);
  o.w += p0 * bf2f(a[3]) + p1 * bf2f(b[3]);
  ((float4*)(out + (size_t)t * 1024))[tid] = o;
}

// ---------------- host launch ----------------
extern "C" void kernel_launch(void* const* d_in, const int* in_sizes, int n_in,
                              void* d_out, int out_size, void* d_ws, size_t ws_size,
                              hipStream_t stream) {
  const float* x    = (const float*)d_in[0];
  const float* ln1w = (const float*)d_in[1];
  const float* ln1b = (const float*)d_in[2];
  const float* ln2w = (const float*)d_in[3];
  const float* ln2b = (const float*)d_in[4];
  const float* inw  = (const float*)d_in[5];
  const float* inb  = (const float*)d_in[6];
  const float* outw = (const float*)d_in[7];
  const float* outb = (const float*)d_in[8];
  const float* gw   = (const float*)d_in[9];
  const float* gb   = (const float*)d_in[10];
  const float* w1   = (const float*)d_in[11];
  const float* b1   = (const float*)d_in[12];
  const float* w2   = (const float*)d_in[13];
  const float* b2   = (const float*)d_in[14];
  float* out = (float*)d_out;
  char* ws = (char*)d_ws;

  // layout (bytes)
  u16* xn1 = (u16*)(ws + 0);              // 16M
  u16* qkv = (u16*)(ws + 16777216);       // 48M
  u16* ctx = (u16*)(ws + 67108864);       // 16M
  u16* hid = (u16*)(ws + 0);              // 128M (overlaps xn1/qkv/ctx, dead by then)
  u16* xn2 = (u16*)(ws + 134217728);      // 16M
  u16* w1t = (u16*)(ws + 150994944);      // 64M (dead after moe1)
  u16* winb  = (u16*)(ws + 218103808);    // 6M  (dead after qkv gemm)
  u16* woutb = (u16*)(ws + 224395264);    // 2M  (dead after outproj)
  u16* w2t = (u16*)(ws + 134217728);      // 64M, written AFTER moe1 (over xn2+w1t head)
  u16* part = (u16*)(ws + 201326592);     // 32M (big-ws path only)

  const bool bigWS = ws_size >= 235471872ull;
  int*   cnt, *ltok, *t2s; float* lprb;
  if (bigWS) {
    cnt  = (int*)(ws + 234881024);
    ltok = (int*)(ws + 234882048);
    lprb = (float*)(ws + 235144192);
    t2s  = (int*)(ws + 235406336);
  } else {
    cnt  = (int*)(ws + 226492416);
    ltok = (int*)(ws + 226492672);
    lprb = (float*)(ws + 226754816);
    t2s  = nullptr;
  }

  // weight prep
  cast_kernel<<<3072, 256, 0, stream>>>(inw, winb, 786432);
  cast_kernel<<<1024, 256, 0, stream>>>(outw, woutb, 262144);
  transpose_cast<<<dim3(64, 16, 8), 256, 0, stream>>>(w1, w1t, 1024, 4096);

  // attention sub-block
  ln1_kernel<<<8192, 256, 0, stream>>>(x, ln1w, ln1b, xn1);
  gemm256<0><<<dim3(12, 32, 1), 512, 0, stream>>>(xn1, winb, 1024, 1024, 3072, 3072,
                                                  inb, nullptr, nullptr, qkv, nullptr, nullptr, nullptr);
  attn_kernel<<<dim3(16, 128), 256, 0, stream>>>(qkv, ctx);
  gemm256<1><<<dim3(4, 32, 1), 512, 0, stream>>>(ctx, woutb, 1024, 1024, 1024, 1024,
                                                 outb, x, out, nullptr, nullptr, nullptr, nullptr);

  // MoE sub-block (top-2 only)
  hipMemsetAsync(cnt, 0, 32, stream);
  ln2_gate_kernel<<<8192, 256, 0, stream>>>(out, ln2w, ln2b, gw, gb, xn2, cnt, ltok, lprb, t2s);
  gemm256<2><<<dim3(16, 32, 8), 512, 0, stream>>>(xn2, w1t, 1024, 1024, 4096, 4096,
                                                  b1, nullptr, nullptr, hid, cnt, ltok, lprb);
  transpose_cast<<<dim3(16, 64, 8), 256, 0, stream>>>(w2, w2t, 4096, 1024);
  if (bigWS) {
    gemm256<3><<<dim3(4, 32, 8), 512, 0, stream>>>(hid, w2t, 4096, 4096, 1024, 1024,
                                                   b2, nullptr, nullptr, part, cnt, ltok, lprb);
    combine_kernel<<<8192, 256, 0, stream>>>(part, cnt, t2s, lprb, out);
  } else {
    gemm256<4><<<dim3(4, 32, 8), 512, 0, stream>>>(hid, w2t, 4096, 4096, 1024, 1024,
                                                   b2, nullptr, out, nullptr, cnt, ltok, lprb);
  }
}